// Round 16
// baseline (163.565 us; speedup 1.0000x reference)
//
#include <hip/hip_runtime.h>
#include <hip/hip_bf16.h>

typedef __attribute__((ext_vector_type(8))) short bf16x8;
typedef __attribute__((ext_vector_type(4))) short short4v;
typedef __attribute__((ext_vector_type(4))) float f32x4;
typedef unsigned int u32;

// ---------- helpers ----------
__device__ __forceinline__ short f2bf(float f) {
    union { float f; u32 i; } c; c.f = f;
    u32 r = c.i + 0x7FFFu + ((c.i >> 16) & 1u);   // RNE
    return (short)(r >> 16);
}
// packed f32x2 -> bf16x2 (RNE), single VALU op; no builtin on gfx950 -> asm
__device__ __forceinline__ u32 cvtpk(float lo, float hi) {
    u32 r;
    asm("v_cvt_pk_bf16_f32 %0, %1, %2" : "=v"(r) : "v"(lo), "v"(hi));
    return r;
}
__device__ __forceinline__ f32x4 mfma16(bf16x8 a, bf16x8 b, f32x4 c) {
    return __builtin_amdgcn_mfma_f32_16x16x32_bf16(a, b, c, 0, 0, 0);
}
// K=16 MFMA: B-operand layout matches QK^T D-layout -> zero-shuffle PV.
__device__ __forceinline__ f32x4 mfma16k16(short4v a, short4v b, f32x4 c) {
#if __has_builtin(__builtin_amdgcn_mfma_f32_16x16x16bf16_1k)
    return __builtin_amdgcn_mfma_f32_16x16x16bf16_1k(a, b, c, 0, 0, 0);
#else
    f32x4 d = c;
    asm volatile("v_mfma_f32_16x16x16_bf16 %0, %1, %2, %0"
                 : "+v"(d) : "v"(a), "v"(b));
    return d;
#endif
}
// bare v_exp_f32 (exp2); logits kept in log2 domain (log2e folded into Q)
__device__ __forceinline__ float fexp2(float x) {
#if __has_builtin(__builtin_amdgcn_exp2f)
    return __builtin_amdgcn_exp2f(x);
#else
    float r; asm("v_exp_f32 %0, %1" : "=v"(r) : "v"(x)); return r;
#endif
}
__device__ __forceinline__ void load_lds16(const void* g, void* l) {
    __builtin_amdgcn_global_load_lds(
        (const __attribute__((address_space(1))) u32*)g,
        (__attribute__((address_space(3))) u32*)l, 16, 0, 0);
}

// ---------- fp32 -> bf16 convert (x + 4 weights fused) ----------
__global__ __launch_bounds__(256) void cvt_all_kernel(
    const float* __restrict__ x, const float* __restrict__ wq,
    const float* __restrict__ wk, const float* __restrict__ wv,
    const float* __restrict__ wo, short* __restrict__ ws) {
    const int XV = (4096 * 1024) / 4;
    const int WV = (1024 * 1024) / 4;
    int i = blockIdx.x * 256 + threadIdx.x;
    const float4* src; short4v* dst; int off;
    if (i < XV)            { src = (const float4*)x;  dst = (short4v*)(ws);           off = i; }
    else if (i < XV + WV)  { src = (const float4*)wq; dst = (short4v*)(ws + 4194304); off = i - XV; }
    else if (i < XV + 2*WV){ src = (const float4*)wk; dst = (short4v*)(ws + 5242880); off = i - XV - WV; }
    else if (i < XV + 3*WV){ src = (const float4*)wv; dst = (short4v*)(ws + 6291456); off = i - XV - 2*WV; }
    else                   { src = (const float4*)wo; dst = (short4v*)(ws + 7340032); off = i - XV - 3*WV; }
    float4 v = src[off];
    short4v o;
    o.x = f2bf(v.x); o.y = f2bf(v.y); o.z = f2bf(v.z); o.w = f2bf(v.w);
    dst[off] = o;
}

// ---------- fused QKV projection: 64x128 tile, depth-2 pipeline, BK=32 ------
// Structure = gemm_out's proven pipelined mainloop (that one achieves ~660
// TF/flop-rate vs qkv's former ~450 at 128x128). Grid (24,64) = 1536 blocks.
// Q scaled by 0.125*log2e. Epilogues = R8's proven 64-row versions.
__global__ __launch_bounds__(256) void gemm_qkv_kernel(
    const short* __restrict__ xb, const short* __restrict__ wqb,
    const short* __restrict__ wkb, const short* __restrict__ wvb,
    short* __restrict__ Qh, short* __restrict__ Kh, short* __restrict__ Vf) {
    __shared__ short lds[18432];   // 3 bufs x 6144 shorts; epilogue 64x132=8448
    const int K = 1024;
    const int wave = threadIdx.x >> 6, lane = threadIdx.x & 63;
    const int lr = lane & 15, lg = lane >> 4;
    const int sel = blockIdx.x >> 3;
    const int nbase = (blockIdx.x & 7) * 128;
    const int mbase = blockIdx.y * 64;
    const short* Bm = (sel == 0) ? wqb : (sel == 1) ? wkb : wvb;
    const int wm = wave >> 1, wn = wave & 1;

    f32x4 acc[2][4];
    #pragma unroll
    for (int i = 0; i < 2; ++i)
        #pragma unroll
        for (int j = 0; j < 4; ++j) acc[i][j] = f32x4{0.f, 0.f, 0.f, 0.f};

    auto STAGE = [&](int buf, int k0) {
        #pragma unroll
        for (int i = 0; i < 3; ++i) {
            int f = wave * 3 + i;          // 4 A-frags + 8 B-frags
            if (f < 4)
                load_lds16(xb + (size_t)(mbase + f*16 + lr)*K + (k0 + lg*8),
                           &lds[buf*6144 + f*512]);
            else
                load_lds16(Bm + (size_t)(nbase + (f-4)*16 + lr)*K + (k0 + lg*8),
                           &lds[buf*6144 + 2048 + (f-4)*512]);
        }
    };
    STAGE(0, 0);
    STAGE(1, 32);
    #pragma unroll 1
    for (int t = 0; t < 32; ++t) {
        if (t < 31)
            asm volatile("s_waitcnt vmcnt(3)" ::: "memory");
        else
            asm volatile("s_waitcnt vmcnt(0)" ::: "memory");
        __builtin_amdgcn_s_barrier();
        asm volatile("" ::: "memory");
        const int cur = (t % 3) * 6144;
        bf16x8 af[2], bfv[4];
        #pragma unroll
        for (int mi = 0; mi < 2; ++mi)
            af[mi] = *(const bf16x8*)&lds[cur + (wm*2 + mi)*512 + lane*8];
        #pragma unroll
        for (int ni = 0; ni < 4; ++ni)
            bfv[ni] = *(const bf16x8*)&lds[cur + 2048 + (wn*4 + ni)*512 + lane*8];
        if (t < 30) STAGE((t + 2) % 3, (t + 2) * 32);
        #pragma unroll
        for (int mi = 0; mi < 2; ++mi)
            #pragma unroll
            for (int ni = 0; ni < 4; ++ni)
                acc[mi][ni] = mfma16(af[mi], bfv[ni], acc[mi][ni]);
    }

    if (sel == 2) {
        #pragma unroll
        for (int mi = 0; mi < 2; ++mi) {
            int m0 = mbase + wm*32 + mi*16 + lg*4;
            #pragma unroll
            for (int ni = 0; ni < 4; ++ni) {
                int nc = nbase + wn*64 + ni*16 + lr;
                int h = nc >> 6, d = nc & 63;
                f32x4 v = acc[mi][ni];
                int bi = m0 >> 11, np = m0 & 2047;
                int c = np >> 6, s = (np >> 4) & 3, lg2 = (np >> 2) & 3;
                int dc = d >> 4, lr2 = d & 15;
                size_t off = ((size_t)(bi*16 + h)*32 + c)*4096
                           + (size_t)((s*4 + dc)*64 + lg2*16 + lr2)*4;
                short4v o;
                o.x = f2bf(v.x); o.y = f2bf(v.y); o.z = f2bf(v.z); o.w = f2bf(v.w);
                *(short4v*)&Vf[off] = o;
            }
        }
    } else {
        short* dstb = (sel == 0) ? Qh : Kh;
        const float sc = (sel == 0) ? 0.125f * 1.44269504f : 1.0f;
        __syncthreads();   // all waves' mainloop LDS reads done before overwrite
        #pragma unroll
        for (int mi = 0; mi < 2; ++mi) {
            int row0 = wm*32 + mi*16 + lg*4;
            #pragma unroll
            for (int ni = 0; ni < 4; ++ni) {
                int col = wn*64 + ni*16 + lr;
                f32x4 v = acc[mi][ni];
                #pragma unroll
                for (int r = 0; r < 4; ++r)
                    lds[(row0 + r)*132 + col] = f2bf(v[r] * sc);
            }
        }
        __syncthreads();
        const int h0 = nbase >> 6;
        const int tid = threadIdx.x;
        #pragma unroll
        for (int it = 0; it < 4; ++it) {
            int L = it*256 + tid;          // 0..1023
            int np_l = L >> 4;             // 0..63
            int t16 = L & 15;
            int P = t16 >> 3;              // head panel 0/1
            int c8 = (t16 & 7) * 8;        // col in shorts
            bf16x8 val = *(const bf16x8*)&lds[np_l*132 + P*64 + c8];
            int m = mbase + np_l; int bi = m >> 11, np = m & 2047;
            *(bf16x8*)&dstb[((size_t)(bi*16 + h0 + P)*2048 + np)*64 + c8] = val;
        }
    }
}

// ---------- output projection: 64x128 tile, depth-2 pipeline, BK=32 ----------
__global__ __launch_bounds__(256) void gemm_out_kernel(
    const short* __restrict__ AO, const short* __restrict__ wob,
    const float* __restrict__ bias, float* __restrict__ out) {
    __shared__ short lds[18432];   // 3 bufs x 6144 shorts (A 2KB | B 4KB)
    const int K = 1024;
    const int wave = threadIdx.x >> 6, lane = threadIdx.x & 63;
    const int lr = lane & 15, lg = lane >> 4;
    const int nbase = blockIdx.x * 128;
    const int mbase = blockIdx.y * 64;
    const int wm = wave >> 1, wn = wave & 1;

    f32x4 acc[2][4];
    #pragma unroll
    for (int i = 0; i < 2; ++i)
        #pragma unroll
        for (int j = 0; j < 4; ++j) acc[i][j] = f32x4{0.f, 0.f, 0.f, 0.f};

    auto STAGE = [&](int buf, int k0) {
        #pragma unroll
        for (int i = 0; i < 3; ++i) {
            int f = wave * 3 + i;          // 4 A-frags + 8 B-frags
            if (f < 4)
                load_lds16(AO + (size_t)(mbase + f*16 + lr)*K + (k0 + lg*8),
                           &lds[buf*6144 + f*512]);
            else
                load_lds16(wob + (size_t)(nbase + (f-4)*16 + lr)*K + (k0 + lg*8),
                           &lds[buf*6144 + 2048 + (f-4)*512]);
        }
    };
    STAGE(0, 0);
    STAGE(1, 32);
    #pragma unroll 1
    for (int t = 0; t < 32; ++t) {
        if (t < 31)
            asm volatile("s_waitcnt vmcnt(3)" ::: "memory");
        else
            asm volatile("s_waitcnt vmcnt(0)" ::: "memory");
        __builtin_amdgcn_s_barrier();
        asm volatile("" ::: "memory");
        const int cur = (t % 3) * 6144;
        bf16x8 af[2], bfv[4];
        #pragma unroll
        for (int mi = 0; mi < 2; ++mi)
            af[mi] = *(const bf16x8*)&lds[cur + (wm*2 + mi)*512 + lane*8];
        #pragma unroll
        for (int ni = 0; ni < 4; ++ni)
            bfv[ni] = *(const bf16x8*)&lds[cur + 2048 + (wn*4 + ni)*512 + lane*8];
        if (t < 30) STAGE((t + 2) % 3, (t + 2) * 32);
        #pragma unroll
        for (int mi = 0; mi < 2; ++mi)
            #pragma unroll
            for (int ni = 0; ni < 4; ++ni)
                acc[mi][ni] = mfma16(af[mi], bfv[ni], acc[mi][ni]);
    }

    #pragma unroll
    for (int mi = 0; mi < 2; ++mi) {
        int m0 = mbase + wm*32 + mi*16 + lg*4;
        #pragma unroll
        for (int ni = 0; ni < 4; ++ni) {
            int nc = nbase + wn*64 + ni*16 + lr;
            float bj = bias[nc];
            f32x4 v = acc[mi][ni];
            #pragma unroll
            for (int r = 0; r < 4; ++r)
                out[(size_t)(m0 + r)*1024 + nc] = v[r] + bj;
        }
    }
}

// ---------- LDS-staged attention (R11/R15 proven version, FROZEN) ----------
__global__ __launch_bounds__(256, 4) void attn_kernel(
    const short* __restrict__ Qh, const short* __restrict__ Kh,
    const short* __restrict__ Vf, short* __restrict__ AO) {
    __shared__ short lds[16384];   // K bufs [0,8192), V bufs [8192,16384)
    const int lane = threadIdx.x & 63;
    const int wave = threadIdx.x >> 6;
    const int lr = lane & 15, lg = lane >> 4;
    const int bid  = blockIdx.x;             // 0..1023
    const int xcd  = bid & 7;
    const int rest = bid >> 3;               // 0..127
    const int u    = 31 - (rest >> 2);       // heavy q-tiles dispatch first
    const int bh   = ((rest & 3) << 3) | xcd;
    const int b = bh >> 4, h = bh & 15;
    const int qbase = u*64 + wave*16;
    const int qa = qbase + lr;
    const short* Q  = Qh + (size_t)bh * (2048 * 64);
    const short* Kg = Kh + (size_t)bh * (2048 * 64);
    const short* Vg = Vf + (size_t)bh * (32 * 4096);

    bf16x8 qf0 = *(const bf16x8*)&Q[(size_t)qa*64 + lg*8];
    bf16x8 qf1 = *(const bf16x8*)&Q[(size_t)qa*64 + 32 + lg*8];

    const int fc0 = wave * 2;   // this wave's staging slots

    auto stageK = [&](int buf, int c) {
        #pragma unroll
        for (int i = 0; i < 2; ++i) {
            int fc = fc0 + i, s = fc >> 1, ch = fc & 1;
            load_lds16(Kg + ((size_t)(c*64 + s*16 + lr)*64 + ch*32 + lg*8),
                       &lds[buf*4096 + fc*512]);
        }
    };
    auto stageV = [&](int buf, int c) {
        #pragma unroll
        for (int i = 0; i < 2; ++i) {
            int fi = fc0 + i;
            load_lds16(Vg + (size_t)c*4096 + fi*512 + lane*8,
                       &lds[8192 + buf*4096 + fi*512]);
        }
    };

    // ================= pass 1: entropy stats =================
    f32x4 sv = {0.f,0.f,0.f,0.f}, tv = {0.f,0.f,0.f,0.f};
    stageK(0, 0);
    #pragma unroll 1
    for (int c = 0; c <= u; ++c) {
        __builtin_amdgcn_s_barrier();
        asm volatile("" ::: "memory");
        if (c < u) {
            stageK((c + 1) & 1, c + 1);
            asm volatile("s_waitcnt vmcnt(2)" ::: "memory");
        } else {
            asm volatile("s_waitcnt vmcnt(0)" ::: "memory");
        }
        __builtin_amdgcn_s_barrier();
        asm volatile("" ::: "memory");
        const int base = (c & 1) * 4096;
        #pragma unroll
        for (int s = 0; s < 4; ++s) {
            int k0 = c*64 + s*16;
            if (k0 <= qbase) {                 // wave-uniform
                bf16x8 kf0 = *(const bf16x8*)&lds[base + (s*2    )*512 + lane*8];
                bf16x8 kf1 = *(const bf16x8*)&lds[base + (s*2 + 1)*512 + lane*8];
                f32x4 d = {0.f,0.f,0.f,0.f};
                d = mfma16(kf0, qf0, d); d = mfma16(kf1, qf1, d);
                if (k0 < qbase) {
                    #pragma unroll
                    for (int r = 0; r < 4; ++r) {
                        float e = fexp2(d[r]); sv[r] += e; tv[r] += e * d[r];
                    }
                } else {                       // diagonal subtile
                    int kb = k0 + lg*4;
                    #pragma unroll
                    for (int r = 0; r < 4; ++r) {
                        float dd = (kb + r <= qa) ? d[r] : -1e30f;
                        float e = fexp2(dd); sv[r] += e; tv[r] += e * dd;
                    }
                }
            }
        }
    }
    float sm = (sv[0] + sv[1]) + (sv[2] + sv[3]);
    float t2m = (tv[0] + tv[1]) + (tv[2] + tv[3]);
    sm += __shfl_xor(sm, 16); t2m += __shfl_xor(t2m, 16);
    sm += __shfl_xor(sm, 32); t2m += __shfl_xor(t2m, 32);
    const float LN2 = 0.69314718f;
    float H = LN2 * (__log2f(sm) - t2m / sm);
    float beta = 1.f;
    if (H > 0.5f)
        beta = fmaxf((((-0.037f*H + 0.481f)*H - 2.3f)*H + 4.917f)*H - 1.791f, 1.f);

    // ================= pass 2: softmax(beta*d) and PV =================
    f32x4 o0 = {0.f,0.f,0.f,0.f}, o1 = {0.f,0.f,0.f,0.f};
    f32x4 o2 = {0.f,0.f,0.f,0.f}, o3 = {0.f,0.f,0.f,0.f};
    f32x4 s2v = {0.f,0.f,0.f,0.f};
    __syncthreads();                           // pass-1 reads done; reuse bufs
    stageK(0, 0); stageV(0, 0);
    #pragma unroll 1
    for (int c = 0; c <= u; ++c) {
        __builtin_amdgcn_s_barrier();
        asm volatile("" ::: "memory");
        if (c < u) {
            stageK((c + 1) & 1, c + 1); stageV((c + 1) & 1, c + 1);
            asm volatile("s_waitcnt vmcnt(4)" ::: "memory");
        } else {
            asm volatile("s_waitcnt vmcnt(0)" ::: "memory");
        }
        __builtin_amdgcn_s_barrier();
        asm volatile("" ::: "memory");
        const int kb_ = (c & 1) * 4096;
        const int vb_ = 8192 + (c & 1) * 4096;
        #pragma unroll
        for (int s = 0; s < 4; ++s) {
            int k0 = c*64 + s*16;
            if (k0 <= qbase) {
                bf16x8 kf0 = *(const bf16x8*)&lds[kb_ + (s*2    )*512 + lane*8];
                bf16x8 kf1 = *(const bf16x8*)&lds[kb_ + (s*2 + 1)*512 + lane*8];
                f32x4 d = {0.f,0.f,0.f,0.f};
                d = mfma16(kf0, qf0, d); d = mfma16(kf1, qf1, d);
                float pv[4];
                if (k0 < qbase) {
                    #pragma unroll
                    for (int r = 0; r < 4; ++r) { pv[r] = fexp2(beta * d[r]); s2v[r] += pv[r]; }
                } else {
                    int kb = k0 + lg*4;
                    #pragma unroll
                    for (int r = 0; r < 4; ++r) {
                        float dd = (kb + r <= qa) ? d[r] : -1e30f;
                        pv[r] = fexp2(beta * dd); s2v[r] += pv[r];
                    }
                }
                union { short4v s4; u32 uu[2]; } pb;
                pb.uu[0] = cvtpk(pv[0], pv[1]);
                pb.uu[1] = cvtpk(pv[2], pv[3]);
                short4v vf0 = *(const short4v*)&lds[vb_ + ((s*4 + 0)*64 + lane)*4];
                short4v vf1 = *(const short4v*)&lds[vb_ + ((s*4 + 1)*64 + lane)*4];
                short4v vf2 = *(const short4v*)&lds[vb_ + ((s*4 + 2)*64 + lane)*4];
                short4v vf3 = *(const short4v*)&lds[vb_ + ((s*4 + 3)*64 + lane)*4];
                o0 = mfma16k16(vf0, pb.s4, o0);
                o1 = mfma16k16(vf1, pb.s4, o1);
                o2 = mfma16k16(vf2, pb.s4, o2);
                o3 = mfma16k16(vf3, pb.s4, o3);
            }
        }
    }
    float s2 = (s2v[0] + s2v[1]) + (s2v[2] + s2v[3]);
    s2 += __shfl_xor(s2, 16); s2 += __shfl_xor(s2, 32);
    float inv = 1.f / s2;

    size_t row = ((size_t)(b*2048 + qa))*1024 + h*64;
    f32x4 oo[4] = {o0, o1, o2, o3};
    #pragma unroll
    for (int dc = 0; dc < 4; ++dc) {
        union { short4v s4; u32 uu[2]; } wv;
        wv.uu[0] = cvtpk(oo[dc][0] * inv, oo[dc][1] * inv);
        wv.uu[1] = cvtpk(oo[dc][2] * inv, oo[dc][3] * inv);
        *(short4v*)&AO[row + dc*16 + lg*4] = wv.s4;
    }
}

// ---------- launch ----------
extern "C" void kernel_launch(void* const* d_in, const int* in_sizes, int n_in,
                              void* d_out, int out_size, void* d_ws, size_t ws_size,
                              hipStream_t stream) {
    const float* x  = (const float*)d_in[0];
    const float* Wq = (const float*)d_in[1];
    const float* Wk = (const float*)d_in[2];
    const float* Wv = (const float*)d_in[3];
    const float* Wo = (const float*)d_in[4];
    const float* bo = (const float*)d_in[5];
    float* out = (float*)d_out;
    short* ws = (short*)d_ws;

    short* xb  = ws;              // [4096][1024] bf16 x
    short* wqb = ws + 4194304;
    short* wkb = ws + 5242880;
    short* wvb = ws + 6291456;
    short* wob = ws + 7340032;
    short* Qh  = ws + 8388608;    // [2][16][2048][64], scaled 0.125*log2e
    short* Kh  = ws + 12582912;   // [2][16][2048][64]
    short* Vf  = ws + 16777216;   // [32 bh][32 chunks][4096] fragment order
    short* AO  = ws + 20971520;   // [4096][1024] attention output

    cvt_all_kernel<<<8192, 256, 0, stream>>>(x, Wq, Wk, Wv, Wo, ws);
    gemm_qkv_kernel<<<dim3(24, 64), 256, 0, stream>>>(xb, wqb, wkb, wvb, Qh, Kh, Vf);
    attn_kernel<<<1024, 256, 0, stream>>>(Qh, Kh, Vf, AO);
    gemm_out_kernel<<<dim3(8, 64), 256, 0, stream>>>(AO, wob, bo, out);
}

// Round 17
// 143.772 us; speedup vs baseline: 1.1377x; 1.1377x over previous
//
#include <hip/hip_runtime.h>
#include <hip/hip_bf16.h>

typedef __attribute__((ext_vector_type(8))) short bf16x8;
typedef __attribute__((ext_vector_type(4))) short short4v;
typedef __attribute__((ext_vector_type(4))) float f32x4;
typedef unsigned int u32;

// ---------- helpers ----------
__device__ __forceinline__ short f2bf(float f) {
    union { float f; u32 i; } c; c.f = f;
    u32 r = c.i + 0x7FFFu + ((c.i >> 16) & 1u);   // RNE
    return (short)(r >> 16);
}
// packed f32x2 -> bf16x2 (RNE), single VALU op; no builtin on gfx950 -> asm
__device__ __forceinline__ u32 cvtpk(float lo, float hi) {
    u32 r;
    asm("v_cvt_pk_bf16_f32 %0, %1, %2" : "=v"(r) : "v"(lo), "v"(hi));
    return r;
}
__device__ __forceinline__ f32x4 mfma16(bf16x8 a, bf16x8 b, f32x4 c) {
    return __builtin_amdgcn_mfma_f32_16x16x32_bf16(a, b, c, 0, 0, 0);
}
// K=16 MFMA: B-operand layout matches QK^T D-layout -> zero-shuffle PV.
__device__ __forceinline__ f32x4 mfma16k16(short4v a, short4v b, f32x4 c) {
#if __has_builtin(__builtin_amdgcn_mfma_f32_16x16x16bf16_1k)
    return __builtin_amdgcn_mfma_f32_16x16x16bf16_1k(a, b, c, 0, 0, 0);
#else
    f32x4 d = c;
    asm volatile("v_mfma_f32_16x16x16_bf16 %0, %1, %2, %0"
                 : "+v"(d) : "v"(a), "v"(b));
    return d;
#endif
}
// bare v_exp_f32 (exp2); logits kept in log2 domain (log2e folded into Q)
__device__ __forceinline__ float fexp2(float x) {
#if __has_builtin(__builtin_amdgcn_exp2f)
    return __builtin_amdgcn_exp2f(x);
#else
    float r; asm("v_exp_f32 %0, %1" : "=v"(r) : "v"(x)); return r;
#endif
}
__device__ __forceinline__ void load_lds16(const void* g, void* l) {
    __builtin_amdgcn_global_load_lds(
        (const __attribute__((address_space(1))) u32*)g,
        (__attribute__((address_space(3))) u32*)l, 16, 0, 0);
}

// ---------- fp32 -> bf16 convert (x + 4 weights fused) ----------
__global__ __launch_bounds__(256) void cvt_all_kernel(
    const float* __restrict__ x, const float* __restrict__ wq,
    const float* __restrict__ wk, const float* __restrict__ wv,
    const float* __restrict__ wo, short* __restrict__ ws) {
    const int XV = (4096 * 1024) / 4;
    const int WV = (1024 * 1024) / 4;
    int i = blockIdx.x * 256 + threadIdx.x;
    const float4* src; short4v* dst; int off;
    if (i < XV)            { src = (const float4*)x;  dst = (short4v*)(ws);           off = i; }
    else if (i < XV + WV)  { src = (const float4*)wq; dst = (short4v*)(ws + 4194304); off = i - XV; }
    else if (i < XV + 2*WV){ src = (const float4*)wk; dst = (short4v*)(ws + 5242880); off = i - XV - WV; }
    else if (i < XV + 3*WV){ src = (const float4*)wv; dst = (short4v*)(ws + 6291456); off = i - XV - 2*WV; }
    else                   { src = (const float4*)wo; dst = (short4v*)(ws + 7340032); off = i - XV - 3*WV; }
    float4 v = src[off];
    short4v o;
    o.x = f2bf(v.x); o.y = f2bf(v.y); o.z = f2bf(v.z); o.w = f2bf(v.w);
    dst[off] = o;
}

// ---------- depth-2 counted-vmcnt GEMM mainloop, 128x128 tile, BK=32 --------
// 3 LDS buffers; STAGE(t) issued at iter t-2, waited at iter t with
// s_waitcnt vmcnt(4) (= keep newest stage in flight) -> ~2 iteration bodies
// of latency cover. NO vmcnt(0) drain in the steady loop (T4). Raw s_barrier
// after the wait; buf(t+2)=buf(t-1) was last read in iter t-1, so the iter-t
// barrier orders reads-before-overwrite.
__device__ __forceinline__ void gemm_mainloop(
    const short* __restrict__ A, const short* __restrict__ Bm,
    short* lds, int mbase, int nbase, int wave, int lane, f32x4 acc[4][4]) {
    const int K = 1024;
    const int lr = lane & 15, lg = lane >> 4;
    const int wm = wave >> 1, wn = wave & 1;
    auto STAGE = [&](int buf, int k0) {
        #pragma unroll
        for (int i = 0; i < 2; ++i) {
            int f = wave * 2 + i;   // 8 A-frags + 8 B-frags over 4 waves
            load_lds16(A  + (size_t)(mbase + f*16 + lr)*K + (k0 + lg*8),
                       &lds[buf*8192 + f*512]);
            load_lds16(Bm + (size_t)(nbase + f*16 + lr)*K + (k0 + lg*8),
                       &lds[buf*8192 + 4096 + f*512]);
        }
    };
    STAGE(0, 0);            // 4 outstanding
    STAGE(1, 32);           // 8 outstanding
    #pragma unroll 1
    for (int t = 0; t < 32; ++t) {
        if (t < 31)
            asm volatile("s_waitcnt vmcnt(4)" ::: "memory");  // STAGE(t) landed
        else
            asm volatile("s_waitcnt vmcnt(0)" ::: "memory");
        __builtin_amdgcn_s_barrier();
        asm volatile("" ::: "memory");
        const int cur = (t % 3) * 8192;
        bf16x8 af[4], bfv[4];
        #pragma unroll
        for (int mi = 0; mi < 4; ++mi)
            af[mi] = *(const bf16x8*)&lds[cur + (wm*4 + mi)*512 + lane*8];
        #pragma unroll
        for (int ni = 0; ni < 4; ++ni)
            bfv[ni] = *(const bf16x8*)&lds[cur + 4096 + (wn*4 + ni)*512 + lane*8];
        if (t < 30) STAGE((t + 2) % 3, (t + 2) * 32);
        #pragma unroll
        for (int mi = 0; mi < 4; ++mi)
            #pragma unroll
            for (int ni = 0; ni < 4; ++ni)
                acc[mi][ni] = mfma16(af[mi], bfv[ni], acc[mi][ni]);
    }
    __syncthreads();   // all LDS traffic done before epilogue reuse
}

// ---------- fused QKV projection (128x128, depth-2 pipeline) ----------
// Q scaled by 0.125*log2e. Q/K epilogue: LDS transpose -> 16-B coalesced
// stores into [bh][np][64]. V epilogue: direct PV-fragment-order stores.
__global__ __launch_bounds__(256) void gemm_qkv_kernel(
    const short* __restrict__ xb, const short* __restrict__ wqb,
    const short* __restrict__ wkb, const short* __restrict__ wvb,
    short* __restrict__ Qh, short* __restrict__ Kh, short* __restrict__ Vf) {
    __shared__ short lds[24576];   // 3 bufs x 8192; epilogue 128x132 = 16896
    const int wave = threadIdx.x >> 6, lane = threadIdx.x & 63;
    const int lr = lane & 15, lg = lane >> 4;
    const int sel = blockIdx.x >> 3;
    const int nbase = (blockIdx.x & 7) * 128;
    const int mbase = blockIdx.y * 128;
    const short* Bm = (sel == 0) ? wqb : (sel == 1) ? wkb : wvb;

    f32x4 acc[4][4];
    #pragma unroll
    for (int i = 0; i < 4; ++i)
        #pragma unroll
        for (int j = 0; j < 4; ++j) acc[i][j] = f32x4{0.f, 0.f, 0.f, 0.f};

    gemm_mainloop(xb, Bm, lds, mbase, nbase, wave, lane, acc);

    const int wm = wave >> 1, wn = wave & 1;
    if (sel == 2) {
        #pragma unroll
        for (int mi = 0; mi < 4; ++mi) {
            int m0 = mbase + wm*64 + mi*16 + lg*4;
            #pragma unroll
            for (int ni = 0; ni < 4; ++ni) {
                int nc = nbase + wn*64 + ni*16 + lr;
                int h = nc >> 6, d = nc & 63;
                f32x4 v = acc[mi][ni];
                int bi = m0 >> 11, np = m0 & 2047;
                int c = np >> 6, s = (np >> 4) & 3, lg2 = (np >> 2) & 3;
                int dc = d >> 4, lr2 = d & 15;
                size_t off = ((size_t)(bi*16 + h)*32 + c)*4096
                           + (size_t)((s*4 + dc)*64 + lg2*16 + lr2)*4;
                short4v o;
                o.x = f2bf(v.x); o.y = f2bf(v.y); o.z = f2bf(v.z); o.w = f2bf(v.w);
                *(short4v*)&Vf[off] = o;
            }
        }
    } else {
        short* dstb = (sel == 0) ? Qh : Kh;
        const float sc = (sel == 0) ? 0.125f * 1.44269504f : 1.0f;
        #pragma unroll
        for (int mi = 0; mi < 4; ++mi) {
            int row0 = wm*64 + mi*16 + lg*4;
            #pragma unroll
            for (int ni = 0; ni < 4; ++ni) {
                int col = wn*64 + ni*16 + lr;
                f32x4 v = acc[mi][ni];
                #pragma unroll
                for (int r = 0; r < 4; ++r)
                    lds[(row0 + r)*132 + col] = f2bf(v[r] * sc);
            }
        }
        __syncthreads();
        const int h0 = nbase >> 6;
        const int tid = threadIdx.x;
        #pragma unroll
        for (int it = 0; it < 8; ++it) {
            int L = it*256 + tid;          // 0..2047
            int np_l = L >> 4;             // 0..127
            int t16 = L & 15;
            int P = t16 >> 3;              // head panel 0/1
            int c8 = (t16 & 7) * 8;        // col in shorts
            bf16x8 val = *(const bf16x8*)&lds[np_l*132 + P*64 + c8];
            int m = mbase + np_l; int bi = m >> 11, np = m & 2047;
            *(bf16x8*)&dstb[((size_t)(bi*16 + h0 + P)*2048 + np)*64 + c8] = val;
        }
    }
}

// ---------- output projection: 64x128 tile, depth-2 pipeline, BK=32 ----------
__global__ __launch_bounds__(256) void gemm_out_kernel(
    const short* __restrict__ AO, const short* __restrict__ wob,
    const float* __restrict__ bias, float* __restrict__ out) {
    __shared__ short lds[18432];   // 3 bufs x 6144 shorts (A 2KB | B 4KB)
    const int K = 1024;
    const int wave = threadIdx.x >> 6, lane = threadIdx.x & 63;
    const int lr = lane & 15, lg = lane >> 4;
    const int nbase = blockIdx.x * 128;
    const int mbase = blockIdx.y * 64;
    const int wm = wave >> 1, wn = wave & 1;

    f32x4 acc[2][4];
    #pragma unroll
    for (int i = 0; i < 2; ++i)
        #pragma unroll
        for (int j = 0; j < 4; ++j) acc[i][j] = f32x4{0.f, 0.f, 0.f, 0.f};

    auto STAGE = [&](int buf, int k0) {
        #pragma unroll
        for (int i = 0; i < 3; ++i) {
            int f = wave * 3 + i;          // 4 A-frags + 8 B-frags
            if (f < 4)
                load_lds16(AO + (size_t)(mbase + f*16 + lr)*K + (k0 + lg*8),
                           &lds[buf*6144 + f*512]);
            else
                load_lds16(wob + (size_t)(nbase + (f-4)*16 + lr)*K + (k0 + lg*8),
                           &lds[buf*6144 + 2048 + (f-4)*512]);
        }
    };
    STAGE(0, 0);
    STAGE(1, 32);
    #pragma unroll 1
    for (int t = 0; t < 32; ++t) {
        if (t < 31)
            asm volatile("s_waitcnt vmcnt(3)" ::: "memory");
        else
            asm volatile("s_waitcnt vmcnt(0)" ::: "memory");
        __builtin_amdgcn_s_barrier();
        asm volatile("" ::: "memory");
        const int cur = (t % 3) * 6144;
        bf16x8 af[2], bfv[4];
        #pragma unroll
        for (int mi = 0; mi < 2; ++mi)
            af[mi] = *(const bf16x8*)&lds[cur + (wm*2 + mi)*512 + lane*8];
        #pragma unroll
        for (int ni = 0; ni < 4; ++ni)
            bfv[ni] = *(const bf16x8*)&lds[cur + 2048 + (wn*4 + ni)*512 + lane*8];
        if (t < 30) STAGE((t + 2) % 3, (t + 2) * 32);
        #pragma unroll
        for (int mi = 0; mi < 2; ++mi)
            #pragma unroll
            for (int ni = 0; ni < 4; ++ni)
                acc[mi][ni] = mfma16(af[mi], bfv[ni], acc[mi][ni]);
    }

    #pragma unroll
    for (int mi = 0; mi < 2; ++mi) {
        int m0 = mbase + wm*32 + mi*16 + lg*4;
        #pragma unroll
        for (int ni = 0; ni < 4; ++ni) {
            int nc = nbase + wn*64 + ni*16 + lr;
            float bj = bias[nc];
            f32x4 v = acc[mi][ni];
            #pragma unroll
            for (int r = 0; r < 4; ++r)
                out[(size_t)(m0 + r)*1024 + nc] = v[r] + bj;
        }
    }
}

// ---------- LDS-staged attention (R11/R15 proven version, FROZEN) ----------
__global__ __launch_bounds__(256, 4) void attn_kernel(
    const short* __restrict__ Qh, const short* __restrict__ Kh,
    const short* __restrict__ Vf, short* __restrict__ AO) {
    __shared__ short lds[16384];   // K bufs [0,8192), V bufs [8192,16384)
    const int lane = threadIdx.x & 63;
    const int wave = threadIdx.x >> 6;
    const int lr = lane & 15, lg = lane >> 4;
    const int bid  = blockIdx.x;             // 0..1023
    const int xcd  = bid & 7;
    const int rest = bid >> 3;               // 0..127
    const int u    = 31 - (rest >> 2);       // heavy q-tiles dispatch first
    const int bh   = ((rest & 3) << 3) | xcd;
    const int b = bh >> 4, h = bh & 15;
    const int qbase = u*64 + wave*16;
    const int qa = qbase + lr;
    const short* Q  = Qh + (size_t)bh * (2048 * 64);
    const short* Kg = Kh + (size_t)bh * (2048 * 64);
    const short* Vg = Vf + (size_t)bh * (32 * 4096);

    bf16x8 qf0 = *(const bf16x8*)&Q[(size_t)qa*64 + lg*8];
    bf16x8 qf1 = *(const bf16x8*)&Q[(size_t)qa*64 + 32 + lg*8];

    const int fc0 = wave * 2;   // this wave's staging slots

    auto stageK = [&](int buf, int c) {
        #pragma unroll
        for (int i = 0; i < 2; ++i) {
            int fc = fc0 + i, s = fc >> 1, ch = fc & 1;
            load_lds16(Kg + ((size_t)(c*64 + s*16 + lr)*64 + ch*32 + lg*8),
                       &lds[buf*4096 + fc*512]);
        }
    };
    auto stageV = [&](int buf, int c) {
        #pragma unroll
        for (int i = 0; i < 2; ++i) {
            int fi = fc0 + i;
            load_lds16(Vg + (size_t)c*4096 + fi*512 + lane*8,
                       &lds[8192 + buf*4096 + fi*512]);
        }
    };

    // ================= pass 1: entropy stats =================
    f32x4 sv = {0.f,0.f,0.f,0.f}, tv = {0.f,0.f,0.f,0.f};
    stageK(0, 0);
    #pragma unroll 1
    for (int c = 0; c <= u; ++c) {
        __builtin_amdgcn_s_barrier();
        asm volatile("" ::: "memory");
        if (c < u) {
            stageK((c + 1) & 1, c + 1);
            asm volatile("s_waitcnt vmcnt(2)" ::: "memory");
        } else {
            asm volatile("s_waitcnt vmcnt(0)" ::: "memory");
        }
        __builtin_amdgcn_s_barrier();
        asm volatile("" ::: "memory");
        const int base = (c & 1) * 4096;
        #pragma unroll
        for (int s = 0; s < 4; ++s) {
            int k0 = c*64 + s*16;
            if (k0 <= qbase) {                 // wave-uniform
                bf16x8 kf0 = *(const bf16x8*)&lds[base + (s*2    )*512 + lane*8];
                bf16x8 kf1 = *(const bf16x8*)&lds[base + (s*2 + 1)*512 + lane*8];
                f32x4 d = {0.f,0.f,0.f,0.f};
                d = mfma16(kf0, qf0, d); d = mfma16(kf1, qf1, d);
                if (k0 < qbase) {
                    #pragma unroll
                    for (int r = 0; r < 4; ++r) {
                        float e = fexp2(d[r]); sv[r] += e; tv[r] += e * d[r];
                    }
                } else {                       // diagonal subtile
                    int kb = k0 + lg*4;
                    #pragma unroll
                    for (int r = 0; r < 4; ++r) {
                        float dd = (kb + r <= qa) ? d[r] : -1e30f;
                        float e = fexp2(dd); sv[r] += e; tv[r] += e * dd;
                    }
                }
            }
        }
    }
    float sm = (sv[0] + sv[1]) + (sv[2] + sv[3]);
    float t2m = (tv[0] + tv[1]) + (tv[2] + tv[3]);
    sm += __shfl_xor(sm, 16); t2m += __shfl_xor(t2m, 16);
    sm += __shfl_xor(sm, 32); t2m += __shfl_xor(t2m, 32);
    const float LN2 = 0.69314718f;
    float H = LN2 * (__log2f(sm) - t2m / sm);
    float beta = 1.f;
    if (H > 0.5f)
        beta = fmaxf((((-0.037f*H + 0.481f)*H - 2.3f)*H + 4.917f)*H - 1.791f, 1.f);

    // ================= pass 2: softmax(beta*d) and PV =================
    f32x4 o0 = {0.f,0.f,0.f,0.f}, o1 = {0.f,0.f,0.f,0.f};
    f32x4 o2 = {0.f,0.f,0.f,0.f}, o3 = {0.f,0.f,0.f,0.f};
    f32x4 s2v = {0.f,0.f,0.f,0.f};
    __syncthreads();                           // pass-1 reads done; reuse bufs
    stageK(0, 0); stageV(0, 0);
    #pragma unroll 1
    for (int c = 0; c <= u; ++c) {
        __builtin_amdgcn_s_barrier();
        asm volatile("" ::: "memory");
        if (c < u) {
            stageK((c + 1) & 1, c + 1); stageV((c + 1) & 1, c + 1);
            asm volatile("s_waitcnt vmcnt(4)" ::: "memory");
        } else {
            asm volatile("s_waitcnt vmcnt(0)" ::: "memory");
        }
        __builtin_amdgcn_s_barrier();
        asm volatile("" ::: "memory");
        const int kb_ = (c & 1) * 4096;
        const int vb_ = 8192 + (c & 1) * 4096;
        #pragma unroll
        for (int s = 0; s < 4; ++s) {
            int k0 = c*64 + s*16;
            if (k0 <= qbase) {
                bf16x8 kf0 = *(const bf16x8*)&lds[kb_ + (s*2    )*512 + lane*8];
                bf16x8 kf1 = *(const bf16x8*)&lds[kb_ + (s*2 + 1)*512 + lane*8];
                f32x4 d = {0.f,0.f,0.f,0.f};
                d = mfma16(kf0, qf0, d); d = mfma16(kf1, qf1, d);
                float pv[4];
                if (k0 < qbase) {
                    #pragma unroll
                    for (int r = 0; r < 4; ++r) { pv[r] = fexp2(beta * d[r]); s2v[r] += pv[r]; }
                } else {
                    int kb = k0 + lg*4;
                    #pragma unroll
                    for (int r = 0; r < 4; ++r) {
                        float dd = (kb + r <= qa) ? d[r] : -1e30f;
                        pv[r] = fexp2(beta * dd); s2v[r] += pv[r];
                    }
                }
                union { short4v s4; u32 uu[2]; } pb;
                pb.uu[0] = cvtpk(pv[0], pv[1]);
                pb.uu[1] = cvtpk(pv[2], pv[3]);
                short4v vf0 = *(const short4v*)&lds[vb_ + ((s*4 + 0)*64 + lane)*4];
                short4v vf1 = *(const short4v*)&lds[vb_ + ((s*4 + 1)*64 + lane)*4];
                short4v vf2 = *(const short4v*)&lds[vb_ + ((s*4 + 2)*64 + lane)*4];
                short4v vf3 = *(const short4v*)&lds[vb_ + ((s*4 + 3)*64 + lane)*4];
                o0 = mfma16k16(vf0, pb.s4, o0);
                o1 = mfma16k16(vf1, pb.s4, o1);
                o2 = mfma16k16(vf2, pb.s4, o2);
                o3 = mfma16k16(vf3, pb.s4, o3);
            }
        }
    }
    float s2 = (s2v[0] + s2v[1]) + (s2v[2] + s2v[3]);
    s2 += __shfl_xor(s2, 16); s2 += __shfl_xor(s2, 32);
    float inv = 1.f / s2;

    size_t row = ((size_t)(b*2048 + qa))*1024 + h*64;
    f32x4 oo[4] = {o0, o1, o2, o3};
    #pragma unroll
    for (int dc = 0; dc < 4; ++dc) {
        union { short4v s4; u32 uu[2]; } wv;
        wv.uu[0] = cvtpk(oo[dc][0] * inv, oo[dc][1] * inv);
        wv.uu[1] = cvtpk(oo[dc][2] * inv, oo[dc][3] * inv);
        *(short4v*)&AO[row + dc*16 + lg*4] = wv.s4;
    }
}

// ---------- launch ----------
extern "C" void kernel_launch(void* const* d_in, const int* in_sizes, int n_in,
                              void* d_out, int out_size, void* d_ws, size_t ws_size,
                              hipStream_t stream) {
    const float* x  = (const float*)d_in[0];
    const float* Wq = (const float*)d_in[1];
    const float* Wk = (const float*)d_in[2];
    const float* Wv = (const float*)d_in[3];
    const float* Wo = (const float*)d_in[4];
    const float* bo = (const float*)d_in[5];
    float* out = (float*)d_out;
    short* ws = (short*)d_ws;

    short* xb  = ws;              // [4096][1024] bf16 x
    short* wqb = ws + 4194304;
    short* wkb = ws + 5242880;
    short* wvb = ws + 6291456;
    short* wob = ws + 7340032;
    short* Qh  = ws + 8388608;    // [2][16][2048][64], scaled 0.125*log2e
    short* Kh  = ws + 12582912;   // [2][16][2048][64]
    short* Vf  = ws + 16777216;   // [32 bh][32 chunks][4096] fragment order
    short* AO  = ws + 20971520;   // [4096][1024] attention output

    cvt_all_kernel<<<8192, 256, 0, stream>>>(x, Wq, Wk, Wv, Wo, ws);
    gemm_qkv_kernel<<<dim3(24, 32), 256, 0, stream>>>(xb, wqb, wkb, wvb, Qh, Kh, Vf);
    attn_kernel<<<1024, 256, 0, stream>>>(Qh, Kh, Vf, AO);
    gemm_out_kernel<<<dim3(8, 64), 256, 0, stream>>>(AO, wob, bo, out);
}